// Round 13
// baseline (690.972 us; speedup 1.0000x reference)
//
#include <hip/hip_runtime.h>
#include <hip/hip_bf16.h>
#include <stdint.h>

#define DEV __device__ __forceinline__

using bf16x8  = __attribute__((ext_vector_type(8))) __bf16;
using floatx4 = __attribute__((ext_vector_type(4))) float;
using int32x8 = __attribute__((ext_vector_type(8))) int;

constexpr int Bb  = 8;
constexpr int Nn  = 4096;
constexpr int Dd  = 128;
constexpr int Pp  = 256;
constexpr int Kk  = 64;
constexpr int BP  = Bb * Pp;     // 2048
constexpr int M2  = BP * Kk;     // 131072
constexpr float EPSBN = 1e-5f;

DEV unsigned short f2bf(float f) {
  uint32_t u = __float_as_uint(f);
  u += 0x7fffu + ((u >> 16) & 1u);
  return (unsigned short)(u >> 16);
}
DEV float bf2f(unsigned short h) { return __uint_as_float(((uint32_t)h) << 16); }

DEV void async_copy16(const void* g, const void* l) {
  __builtin_amdgcn_global_load_lds(
      (__attribute__((address_space(1))) uint32_t*)(uintptr_t)g,
      (__attribute__((address_space(3))) uint32_t*)(uint32_t)(uintptr_t)l,
      16, 0, 0);
}

// ---------------- prep: fold BN params, zero output scalar ----------------
__global__ void prep_k(const float* g1, const float* be1, const float* m1, const float* v1, const float* cb1,
                       const float* g2, const float* be2, const float* m2, const float* v2, const float* cb2,
                       float* sc1, float* sh1, float* sc2, float* sh2, float* out) {
  int t = threadIdx.x;  // 1024
  float s1 = g1[t] * rsqrtf(v1[t] + EPSBN);
  sc1[t] = s1; sh1[t] = (cb1[t] - m1[t]) * s1 + be1[t];
  float s2 = g2[t] * rsqrtf(v2[t] + EPSBN);
  sc2[t] = s2; sh2[t] = (cb2[t] - m2[t]) * s2 + be2[t];
  if (t == 0) out[0] = 0.f;
}

// ---------------- LDS-tiled transpose fp32[Kd][Nd] -> bf16[n][k] ----------------
__global__ void cvt16(const float* __restrict__ in, unsigned short* __restrict__ out, int Kd, int Nd) {
  __shared__ float ts[32][33];
  int tx = threadIdx.x & 31, ty = threadIdx.x >> 5;
  int n0 = blockIdx.x * 32, k0 = blockIdx.y * 32;
#pragma unroll
  for (int r = 0; r < 4; ++r)
    ts[ty + 8 * r][tx] = in[(size_t)(k0 + ty + 8 * r) * Nd + n0 + tx];
  __syncthreads();
#pragma unroll
  for (int r = 0; r < 4; ++r)
    out[(size_t)(n0 + ty + 8 * r) * Kd + k0 + tx] = f2bf(ts[tx][ty + 8 * r]);
}

// ---------------- LDS-tiled transpose fp32[Kd][Nd] -> fp8 e4m3 [n][k] ----------------
__global__ void cvt8(const float* __restrict__ in, uint8_t* __restrict__ out, int Kd, int Nd) {
  __shared__ float ts[32][33];
  int tx = threadIdx.x & 31, ty = threadIdx.x >> 5;
  int n0 = blockIdx.x * 32, k0 = blockIdx.y * 32;
#pragma unroll
  for (int r = 0; r < 4; ++r)
    ts[ty + 8 * r][tx] = in[(size_t)(k0 + ty + 8 * r) * Nd + n0 + tx];
  __syncthreads();
#pragma unroll
  for (int r = 0; r < 4; ++r) {
    float v = ts[tx][ty + 8 * r];
    int w = __builtin_amdgcn_cvt_pk_fp8_f32(v, v, 0, false);
    out[(size_t)(n0 + ty + 8 * r) * Kd + k0 + tx] = (uint8_t)(w & 0xff);
  }
}

// ---------------- FPS: 4 waves, 16 pts/lane, lean u64 exchange (183us, R10) ----------------
#define DPPF(v, CTRL) __uint_as_float((uint32_t)__builtin_amdgcn_update_dpp( \
    (int)__float_as_uint(v), (int)__float_as_uint(v), CTRL, 0xF, 0xF, false))
#define DPPI(v, CTRL) __builtin_amdgcn_update_dpp(v, v, CTRL, 0xF, 0xF, false)
#define RSTEP2(CTRL) { \
    float od = DPPF(bv, CTRL); \
    int oi = DPPI(bi, CTRL); \
    bool tk = (od > bv) || (od == bv && oi < bi); \
    bv = tk ? od : bv; bi = tk ? oi : bi; }

__global__ __launch_bounds__(256)
void fps_k(const float* __restrict__ xyz, float* __restrict__ pxyz) {
  int b = blockIdx.x, tid = threadIdx.x;
  int lane = tid & 63, wv = tid >> 6;
  __shared__ float xs[Nn], ys[Nn], zs[Nn];   // coord mirror, 48 KB
  __shared__ uint64_t cand[2][4];
  float xr[16], yr[16], zr[16], md[16];
#pragma unroll
  for (int j = 0; j < 16; ++j) {
    int i = tid + j * 256;
    const float* q = &xyz[(size_t)(b * Nn + i) * 3];
    float x = q[0], y = q[1], z = q[2];
    xr[j] = x; yr[j] = y; zr[j] = z; md[j] = 1e10f;
    xs[i] = x; ys[i] = y; zs[i] = z;
  }
  __syncthreads();   // mirror visible to all waves
  const float* q0 = &xyz[(size_t)(b * Nn) * 3];
  float lx = q0[0], ly = q0[1], lz = q0[2];
  if (tid == 0) {
    pxyz[(size_t)(b * Pp) * 3 + 0] = lx;
    pxyz[(size_t)(b * Pp) * 3 + 1] = ly;
    pxyz[(size_t)(b * Pp) * 3 + 2] = lz;
  }
  for (int p = 1; p < Pp; ++p) {
    float bv = -1.f; int bi = 0x7fffffff;
#pragma unroll
    for (int j = 0; j < 16; ++j) {
      // no-fma arithmetic to match numpy (x-l)^2 sum bit pattern
      float dx = __fadd_rn(xr[j], -lx);
      float dy = __fadd_rn(yr[j], -ly);
      float dz = __fadd_rn(zr[j], -lz);
      float d = __fadd_rn(__fadd_rn(__fmul_rn(dx, dx), __fmul_rn(dy, dy)), __fmul_rn(dz, dz));
      float m = fminf(md[j], d);
      md[j] = m;
      if (m > bv) { bv = m; bi = tid + j * 256; }   // strict >: lowest idx on tie
    }
    // DPP wave64 argmax (d,idx) -> lane 63
    RSTEP2(0x111) RSTEP2(0x112) RSTEP2(0x114) RSTEP2(0x118) RSTEP2(0x142) RSTEP2(0x143)
    int s = p & 1;
    if (lane == 63)
      cand[s][wv] = ((uint64_t)(uint32_t)__float_as_uint(bv) << 32) |
                    (uint32_t)(0x7fffffff - bi);
    __syncthreads();
    uint64_t k0 = cand[s][0], k1 = cand[s][1], k2 = cand[s][2], k3 = cand[s][3];
    uint64_t ka = (k0 > k1) ? k0 : k1;
    uint64_t kb = (k2 > k3) ? k2 : k3;
    uint64_t kw = (ka > kb) ? ka : kb;
    int wi = 0x7fffffff - (int)(uint32_t)(kw & 0xffffffffu);
    lx = xs[wi]; ly = ys[wi]; lz = zs[wi];   // broadcast reads
    if (tid == 0) {
      pxyz[(size_t)(b * Pp + p) * 3 + 0] = lx;
      pxyz[(size_t)(b * Pp + p) * 3 + 1] = ly;
      pxyz[(size_t)(b * Pp + p) * 3 + 2] = lz;
    }
  }
}

// ---------------- grouping: 64-NN radix select + feat maxpool + gxyz ----------------
__global__ __launch_bounds__(256)
void group_k(const float* __restrict__ xyz, const float* __restrict__ feat,
             const float* __restrict__ pxyz, unsigned short* __restrict__ pfb,
             float* __restrict__ gxyz) {
  int bp = blockIdx.x, tid = threadIdx.x;
  int b = bp >> 8;
  __shared__ uint32_t dbits[Nn];
  __shared__ uint32_t hist[256];
  __shared__ int sel[64];
  __shared__ uint32_t svDigit, svWant, svClt, svCeq;
  __shared__ float red[256];
  float px = pxyz[(size_t)bp * 3], py = pxyz[(size_t)bp * 3 + 1], pz = pxyz[(size_t)bp * 3 + 2];
  for (int i = tid; i < Nn; i += 256) {
    const float* q = &xyz[(size_t)(b * Nn + i) * 3];
    float dx = q[0] - px, dy = q[1] - py, dz = q[2] - pz;
    dbits[i] = __float_as_uint(dx * dx + dy * dy + dz * dz);
  }
  uint32_t prefix = 0, want = 64;
  for (int shift = 24; shift >= 0; shift -= 8) {
    __syncthreads();
    hist[tid] = 0;
    __syncthreads();
    for (int i = tid; i < Nn; i += 256) {
      uint32_t v = dbits[i];
      bool match = (shift == 24) || ((v >> (shift + 8)) == prefix);
      if (match) atomicAdd(&hist[(v >> shift) & 255], 1u);
    }
    __syncthreads();
    uint32_t myh = hist[tid];
    for (int off = 1; off < 256; off <<= 1) {
      uint32_t o = (tid >= off) ? hist[tid - off] : 0u;
      __syncthreads();
      hist[tid] += o;
      __syncthreads();
    }
    uint32_t cum = hist[tid];
    uint32_t prev = cum - myh;
    if (prev < want && want <= cum) { svDigit = (uint32_t)tid; svWant = want - prev; }
    __syncthreads();
    prefix = (prefix << 8) | svDigit;
    want = svWant;
  }
  uint32_t tval = prefix;
  if (tid == 0) { svClt = 0; svCeq = 0; }
  __syncthreads();
  for (int i = tid; i < Nn; i += 256) {
    if (dbits[i] < tval) { uint32_t pos = atomicAdd(&svClt, 1u); sel[pos] = i; }
  }
  __syncthreads();
  uint32_t clt = svClt;
  for (int i = tid; i < Nn; i += 256) {
    if (dbits[i] == tval) {
      uint32_t pos = atomicAdd(&svCeq, 1u);
      if (clt + pos < 64) sel[clt + pos] = i;
    }
  }
  __syncthreads();
  if (tid < 192) {
    int k = tid / 3, c = tid - k * 3;
    float sub = (c == 0) ? px : (c == 1) ? py : pz;
    gxyz[(size_t)bp * 192 + tid] = xyz[(size_t)(b * Nn + sel[k]) * 3 + c] - sub;
  }
  int dch = tid & 127, half = tid >> 7;
  float m = -1e30f;
  for (int k = half * 32; k < half * 32 + 32; ++k)
    m = fmaxf(m, feat[(size_t)(b * Nn + sel[k]) * Dd + dch]);
  red[tid] = m;
  __syncthreads();
  if (half == 0) pfb[(size_t)bp * Dd + dch] = f2bf(fmaxf(m, red[tid + 128]));
}

// ---------------- bf16 MFMA GEMM: C[M,N] = A[M,K] * Bt[N,K]^T ----------------
template <int EPI>
__global__ __launch_bounds__(256)
void gemm_bt(const unsigned short* __restrict__ A, const unsigned short* __restrict__ Bt,
             float* __restrict__ Cf, unsigned short* __restrict__ Ch,
             const float* __restrict__ p0,
             int Npar, int Kd, int nbn) {
  __shared__ __align__(16) unsigned short As[128 * 32];
  __shared__ __align__(16) unsigned short Bs[128 * 32];
  const int tid = threadIdx.x;
  const int lane = tid & 63, wid = tid >> 6;
  const int bn = blockIdx.x % nbn, bm = blockIdx.x / nbn;
  const int m0 = bm * 128, n0 = bn * 128;
  const int quad = lane >> 4, l15 = lane & 15;
  const int wm = wid & 1, wn = wid >> 1;

  floatx4 acc[4][4];
#pragma unroll
  for (int i = 0; i < 4; ++i)
#pragma unroll
    for (int j = 0; j < 4; ++j) acc[i][j] = floatx4{0.f, 0.f, 0.f, 0.f};

  const int c0i = tid, c1i = tid + 256;
  const int r0 = c0i >> 2, o0 = (c0i & 3) * 8;
  const int r1 = c1i >> 2, o1 = (c1i & 3) * 8;

  for (int k0 = 0; k0 < Kd; k0 += 32) {
    async_copy16(A + (size_t)(m0 + r0) * Kd + k0 + o0, &As[c0i * 8]);
    async_copy16(A + (size_t)(m0 + r1) * Kd + k0 + o1, &As[c1i * 8]);
    async_copy16(Bt + (size_t)(n0 + r0) * Kd + k0 + o0, &Bs[c0i * 8]);
    async_copy16(Bt + (size_t)(n0 + r1) * Kd + k0 + o1, &Bs[c1i * 8]);
    __syncthreads();
    const bf16x8* Ap = reinterpret_cast<const bf16x8*>(As);
    const bf16x8* Bp = reinterpret_cast<const bf16x8*>(Bs);
    bf16x8 af[4], bfv[4];
#pragma unroll
    for (int t = 0; t < 4; ++t) {
      af[t]  = Ap[(wm * 64 + t * 16 + l15) * 4 + quad];
      bfv[t] = Bp[(wn * 64 + t * 16 + l15) * 4 + quad];
    }
#pragma unroll
    for (int mt = 0; mt < 4; ++mt)
#pragma unroll
      for (int nt = 0; nt < 4; ++nt)
        acc[mt][nt] = __builtin_amdgcn_mfma_f32_16x16x32_bf16(af[mt], bfv[nt], acc[mt][nt], 0, 0, 0);
    __syncthreads();
  }

  const int rowBase = m0 + wm * 64 + quad * 4;
  const int colBase = n0 + wn * 64 + l15;

  if (EPI == 0) {
#pragma unroll
    for (int mt = 0; mt < 4; ++mt)
#pragma unroll
      for (int nt = 0; nt < 4; ++nt)
#pragma unroll
        for (int r = 0; r < 4; ++r)
          Cf[(size_t)(rowBase + mt * 16 + r) * Npar + colBase + nt * 16] = acc[mt][nt][r];
  } else {
#pragma unroll
    for (int nt = 0; nt < 4; ++nt) {
      float bias = p0[colBase + nt * 16];
#pragma unroll
      for (int mt = 0; mt < 4; ++mt)
#pragma unroll
        for (int r = 0; r < 4; ++r) {
          float v = fmaxf(acc[mt][nt][r] + bias, 0.f);
          Ch[(size_t)(rowBase + mt * 16 + r) * Npar + colBase + nt * 16] = f2bf(v);
        }
    }
  }
}

// ---------------- conv2 MX-fp8, h1 FUSED: 32-row block, full-K A in LDS ----------------
// R12: FETCH stuck at 532 MB (4xA) - A restages never hit L2 (working set/XCD
// 7.3 MB > 4 MB). Fix: never touch h1 in global at all. Block = 32 M-rows
// (one half-patch, bp=bm>>1); A-slab (32x1024 fp8, 32 KB, XOR-swizzled) is
// COMPUTED in-kernel from u1/cw1/coarse/sc1/sh1 (per-col params row-invariant:
// 7 float4/thread loaded once). Then bn x k0 loops stage only B (16 KB, L2-
// resident 1 MB). Epilogue: block-complete conv3 rowsums -> direct fine store.
__global__ __launch_bounds__(256)
void gemm_mx3(const float* __restrict__ u1, const float* __restrict__ cw1,
              const float* __restrict__ coarse, const float* __restrict__ sc1,
              const float* __restrict__ sh1,
              const uint8_t* __restrict__ Bt,
              const float* __restrict__ p0, const float* __restrict__ p1,
              const float* __restrict__ cw3, const float* __restrict__ cb3,
              float* __restrict__ fine) {
  __shared__ __align__(128) uint8_t As[32 * 1024];   // 32 KB, full-K
  __shared__ __align__(128) uint8_t Bs[128 * 128];   // 16 KB per (bn,k0) tile
  __shared__ float fsum[2][2][16][3];                // [wm][wn][rowLocal][xyz]
  const int tid = threadIdx.x;
  const int lane = tid & 63, wid = tid >> 6;
  const int bm = blockIdx.x;                          // 4096 blocks
  const int quad = lane >> 4, l15 = lane & 15;
  const int wm = wid & 1, wn = wid >> 1;
  const int bp = bm >> 1;                             // patch (32 | 64)

  // ---- build A-slab: thread t owns cols [4t,4t+4) (bytes == h1 cols) ----
  {
    int n0c = tid * 4;
    float4 un  = *(const float4*)&u1[(size_t)bp * 1024 + n0c];
    float4 a0  = *(const float4*)&cw1[128 * 1024 + n0c];
    float4 a1  = *(const float4*)&cw1[129 * 1024 + n0c];
    float4 b0  = *(const float4*)&cw1[130 * 1024 + n0c];
    float4 b1v = *(const float4*)&cw1[131 * 1024 + n0c];
    float4 b2v = *(const float4*)&cw1[132 * 1024 + n0c];
    float4 sc  = *(const float4*)&sc1[n0c];
    float4 sh  = *(const float4*)&sh1[n0c];
    const float sxv[4] = {-0.05f, 0.05f, -0.05f, 0.05f};
    const float syv[4] = {-0.05f, -0.05f, 0.05f, 0.05f};
    uint32_t* Aw = (uint32_t*)As;
    int gc = tid >> 2;                                // 16B chunk 0..63
    int dw = tid & 3;                                 // dword in chunk
    for (int row = 0; row < 32; ++row) {
      int gi = row & 3;                               // grid seed index
      int j = (bm & 1) * 8 + (row >> 2);              // coarse point index
      float c0 = coarse[(size_t)bp * 48 + j * 3 + 0];
      float c1 = coarse[(size_t)bp * 48 + j * 3 + 1];
      float c2 = coarse[(size_t)bp * 48 + j * 3 + 2];
      float sx = sxv[gi], sy = syv[gi];
      float x0 = un.x + sx * a0.x + sy * a1.x + c0 * b0.x + c1 * b1v.x + c2 * b2v.x;
      float x1 = un.y + sx * a0.y + sy * a1.y + c0 * b0.y + c1 * b1v.y + c2 * b2v.y;
      float x2 = un.z + sx * a0.z + sy * a1.z + c0 * b0.z + c1 * b1v.z + c2 * b2v.z;
      float x3 = un.w + sx * a0.w + sy * a1.w + c0 * b0.w + c1 * b1v.w + c2 * b2v.w;
      float v0 = fmaxf(x0 * sc.x + sh.x, 0.f);
      float v1 = fmaxf(x1 * sc.y + sh.y, 0.f);
      float v2 = fmaxf(x2 * sc.z + sh.z, 0.f);
      float v3 = fmaxf(x3 * sc.w + sh.w, 0.f);
      int w = __builtin_amdgcn_cvt_pk_fp8_f32(v0, v1, 0, false);
      w = __builtin_amdgcn_cvt_pk_fp8_f32(v2, v3, w, true);
      int phys = (gc & ~7) | ((gc & 7) ^ (row & 7));  // 16B-chunk XOR swizzle
      Aw[row * 256 + phys * 4 + dw] = (uint32_t)w;
    }
  }
  float fp[4][3];
#pragma unroll
  for (int r = 0; r < 4; ++r) fp[r][0] = fp[r][1] = fp[r][2] = 0.f;
  __syncthreads();   // A-slab visible

  const uint4* Ap = (const uint4*)As;
  const int rm = wm * 16 + l15;                       // A row 0..31
  const int swm = rm & 7;

  for (int bn = 0; bn < 8; ++bn) {
    const int n0 = bn * 128;
    floatx4 acc[4];
#pragma unroll
    for (int j = 0; j < 4; ++j) acc[j] = floatx4{0.f, 0.f, 0.f, 0.f};

    for (int k0 = 0; k0 < 1024; k0 += 128) {
#pragma unroll
      for (int c = 0; c < 4; ++c) {
        int ci = c * 256 + tid;            // 1024 16B-chunks of B
        int row = ci >> 3, cp = ci & 7;
        int cc = cp ^ (row & 7);
        async_copy16(Bt + (size_t)(n0 + row) * 1024 + k0 + cc * 16, &Bs[ci * 16]);
      }
      __syncthreads();
      const uint4* Bp = (const uint4*)Bs;
      int kc = k0 >> 4;                    // base 16B-chunk (multiple of 8)
      uint4 alo = Ap[rm * 64 + kc + ((2 * quad) ^ swm)];
      uint4 ahi = Ap[rm * 64 + kc + ((2 * quad + 1) ^ swm)];
      int32x8 av = int32x8{(int)alo.x, (int)alo.y, (int)alo.z, (int)alo.w,
                           (int)ahi.x, (int)ahi.y, (int)ahi.z, (int)ahi.w};
      int32x8 bv[4];
#pragma unroll
      for (int nt = 0; nt < 4; ++nt) {
        int rn = wn * 64 + nt * 16 + l15;
        int swn = rn & 7;
        uint4 blo = Bp[rn * 8 + ((2 * quad) ^ swn)];
        uint4 bhi = Bp[rn * 8 + ((2 * quad + 1) ^ swn)];
        bv[nt] = int32x8{(int)blo.x, (int)blo.y, (int)blo.z, (int)blo.w,
                         (int)bhi.x, (int)bhi.y, (int)bhi.z, (int)bhi.w};
      }
#pragma unroll
      for (int nt = 0; nt < 4; ++nt)
        acc[nt] = __builtin_amdgcn_mfma_scale_f32_16x16x128_f8f6f4(
            av, bv[nt], acc[nt], 0, 0, 0, 127, 0, 127);
      __syncthreads();
    }

#pragma unroll
    for (int nt = 0; nt < 4; ++nt) {
      int col = n0 + wn * 64 + nt * 16 + l15;
      float sc = p0[col], sh = p1[col];
      float c0 = cw3[col * 3], c1 = cw3[col * 3 + 1], c2 = cw3[col * 3 + 2];
#pragma unroll
      for (int r = 0; r < 4; ++r) {
        float v = fmaxf(acc[nt][r] * sc + sh, 0.f);
        fp[r][0] += v * c0; fp[r][1] += v * c1; fp[r][2] += v * c2;
      }
    }
  }

#pragma unroll
  for (int off = 1; off < 16; off <<= 1)
#pragma unroll
    for (int r = 0; r < 4; ++r)
#pragma unroll
      for (int i = 0; i < 3; ++i)
        fp[r][i] += __shfl_xor(fp[r][i], off, 64);
  if (l15 == 0) {
#pragma unroll
    for (int r = 0; r < 4; ++r)
#pragma unroll
      for (int i = 0; i < 3; ++i)
        fsum[wm][wn][quad * 4 + r][i] = fp[r][i];
  }
  __syncthreads();
  if (tid < 96) {                                    // 32 rows x 3 (< 256 thr)
    int row = tid / 3, i = tid - row * 3;
    float s = fsum[row >> 4][0][row & 15][i] + fsum[row >> 4][1][row & 15][i];
    int g = bm * 32 + row;
    int j = (bm & 1) * 8 + ((row & 31) >> 2);
    fine[(size_t)g * 3 + i] = s + cb3[i] + coarse[(size_t)bp * 48 + j * 3 + i];
  }
}

// ---------------- coarse = h2m @ w3 + b3 (fp32, thin N=48) ----------------
__global__ __launch_bounds__(256)
void coarse_k(const unsigned short* __restrict__ h2m, const float* __restrict__ w3,
              const float* __restrict__ b3, float* __restrict__ coarse) {
  int r = blockIdx.x, tid = threadIdx.x;
  __shared__ float hrow[1024];
  __shared__ float part[192];
  for (int i = tid; i < 1024; i += 256) hrow[i] = bf2f(h2m[(size_t)r * 1024 + i]);
  __syncthreads();
  if (tid < 192) {
    int j = tid % 48, seg = tid / 48;
    float acc = 0.f;
    for (int k = seg * 256; k < seg * 256 + 256; ++k) acc += hrow[k] * w3[(size_t)k * 48 + j];
    part[tid] = acc;
  }
  __syncthreads();
  if (tid < 48)
    coarse[(size_t)r * 48 + tid] = part[tid] + part[tid + 48] + part[tid + 96] + part[tid + 144] + b3[tid];
}

// ---------------- chamfer: one wave per patch ----------------
__global__ __launch_bounds__(256)
void chamfer_k(const float* __restrict__ fine, const float* __restrict__ gxyz,
               float* __restrict__ out) {
  int tid = threadIdx.x, wv = tid >> 6, lane = tid & 63;
  int bp = blockIdx.x * 4 + wv;
  __shared__ float sf[4][64][3], sg[4][64][3];
  const float* fr = &fine[(size_t)(bp * 64 + lane) * 3];
  const float* gr = &gxyz[(size_t)(bp * 64 + lane) * 3];
  sf[wv][lane][0] = fr[0]; sf[wv][lane][1] = fr[1]; sf[wv][lane][2] = fr[2];
  sg[wv][lane][0] = gr[0]; sg[wv][lane][1] = gr[1]; sg[wv][lane][2] = gr[2];
  __syncthreads();
  float f0 = sf[wv][lane][0], f1 = sf[wv][lane][1], f2 = sf[wv][lane][2];
  float g0 = sg[wv][lane][0], g1 = sg[wv][lane][1], g2 = sg[wv][lane][2];
  float rmin = 1e30f, cmin = 1e30f;
  for (int j = 0; j < 64; ++j) {
    float dx = f0 - sg[wv][j][0], dy = f1 - sg[wv][j][1], dz = f2 - sg[wv][j][2];
    rmin = fminf(rmin, dx * dx + dy * dy + dz * dz);
    float ex = sf[wv][j][0] - g0, ey = sf[wv][j][1] - g1, ez = sf[wv][j][2] - g2;
    cmin = fminf(cmin, ex * ex + ey * ey + ez * ez);
  }
  float tot = rmin + cmin;
  for (int off = 32; off; off >>= 1) tot += __shfl_down(tot, off, 64);
  if (lane == 0) atomicAdd(out, tot * (1.0f / 131072.0f));
}

extern "C" void kernel_launch(void* const* d_in, const int* in_sizes, int n_in,
                              void* d_out, int out_size, void* d_ws, size_t ws_size,
                              hipStream_t stream) {
  (void)in_sizes; (void)n_in; (void)out_size; (void)ws_size;
  const float* xyz = (const float*)d_in[0];
  const float* feat = (const float*)d_in[1];
  const float* w1 = (const float*)d_in[2];
  const float* b1 = (const float*)d_in[3];
  const float* w2 = (const float*)d_in[4];
  const float* b2 = (const float*)d_in[5];
  const float* w3 = (const float*)d_in[6];
  const float* b3 = (const float*)d_in[7];
  const float* cw1 = (const float*)d_in[8];
  const float* cb1 = (const float*)d_in[9];
  const float* g1 = (const float*)d_in[10];
  const float* be1 = (const float*)d_in[11];
  const float* m1 = (const float*)d_in[12];
  const float* v1 = (const float*)d_in[13];
  const float* cw2 = (const float*)d_in[14];
  const float* cb2 = (const float*)d_in[15];
  const float* g2 = (const float*)d_in[16];
  const float* be2 = (const float*)d_in[17];
  const float* m2 = (const float*)d_in[18];
  const float* v2 = (const float*)d_in[19];
  const float* cw3 = (const float*)d_in[20];
  const float* cb3 = (const float*)d_in[21];
  float* out = (float*)d_out;

  uint8_t* ws = (uint8_t*)d_ws;
  size_t off = 0;
  auto alloc = [&](size_t bytes) {
    void* p = ws + off;
    off = (off + bytes + 255) & ~(size_t)255;
    return p;
  };
  float*          pxyz  = (float*)alloc((size_t)BP * 3 * 4);
  unsigned short* w1t   = (unsigned short*)alloc((size_t)1024 * 128 * 2);
  unsigned short* cw1t  = (unsigned short*)alloc((size_t)1024 * 128 * 2);
  unsigned short* w2t   = (unsigned short*)alloc((size_t)1024 * 1024 * 2);
  uint8_t*        cw2t8 = (uint8_t*)alloc((size_t)1024 * 1024);
  float*          sc1   = (float*)alloc(4096);
  float*          sh1   = (float*)alloc(4096);
  float*          sc2   = (float*)alloc(4096);
  float*          sh2   = (float*)alloc(4096);
  unsigned short* pfb   = (unsigned short*)alloc((size_t)BP * 128 * 2);
  float*          gxyz  = (float*)alloc((size_t)BP * 64 * 3 * 4);
  float*          u1    = (float*)alloc((size_t)BP * 1024 * 4);
  unsigned short* hb    = (unsigned short*)alloc((size_t)BP * 1024 * 2);
  unsigned short* h2m   = (unsigned short*)alloc((size_t)BP * 1024 * 2);
  float*          coarse = (float*)alloc((size_t)BP * 48 * 4);
  float*          fine  = (float*)alloc((size_t)M2 * 3 * 4);

  prep_k<<<1, 1024, 0, stream>>>(g1, be1, m1, v1, cb1, g2, be2, m2, v2, cb2,
                                 sc1, sh1, sc2, sh2, out);
  cvt16<<<dim3(1024 / 32, 128 / 32), 256, 0, stream>>>(w1, w1t, 128, 1024);
  cvt16<<<dim3(1024 / 32, 128 / 32), 256, 0, stream>>>(cw1, cw1t, 128, 1024);
  cvt16<<<dim3(1024 / 32, 1024 / 32), 256, 0, stream>>>(w2, w2t, 1024, 1024);
  cvt8<<<dim3(1024 / 32, 1024 / 32), 256, 0, stream>>>(cw2, cw2t8, 1024, 1024);
  fps_k<<<Bb, 256, 0, stream>>>(xyz, pxyz);
  group_k<<<BP, 256, 0, stream>>>(xyz, feat, pxyz, pfb, gxyz);
  // u1 = pf @ cw1[:128]   (fp32 out)
  gemm_bt<0><<<(2048 / 128) * 8, 256, 0, stream>>>(pfb, cw1t, u1, nullptr, nullptr,
                                                   1024, 128, 8);
  // h = relu(pf @ w1 + b1)
  gemm_bt<1><<<(2048 / 128) * 8, 256, 0, stream>>>(pfb, w1t, nullptr, hb, b1,
                                                   1024, 128, 8);
  // h2m = relu(h @ w2 + b2)
  gemm_bt<1><<<(2048 / 128) * 8, 256, 0, stream>>>(hb, w2t, nullptr, h2m, b2,
                                                   1024, 1024, 8);
  coarse_k<<<2048, 256, 0, stream>>>(h2m, w3, b3, coarse);
  // conv2 MX-fp8, h1 fused in-kernel (no h1 buffer, no chunking)
  gemm_mx3<<<M2 / 32, 256, 0, stream>>>(u1, cw1, coarse, sc1, sh1,
                                        cw2t8, sc2, sh2, cw3, cb3, fine);
  chamfer_k<<<BP / 4, 256, 0, stream>>>(fine, gxyz, out);
}